// Round 1
// baseline (121.709 us; speedup 1.0000x reference)
//
#include <hip/hip_runtime.h>

// PointPillarsScatter: canvas[b, :, y, x] = feat[p, :], last-writer-wins.
// Strategy: winner[b*H*W + y*W + x] = max(p)+1 via atomicMax (deterministic
// last-writer), then a single coalesced gather writes the whole canvas
// (zeros included) as float4 — no full-canvas memset, no RMW write traffic.

constexpr int HH = 496;
constexpr int WW = 432;
constexpr int CC = 64;
constexpr int HWp = HH * WW;   // 214272
constexpr int W4 = WW / 4;     // 108

__global__ void k_winner(const int* __restrict__ coords, int* __restrict__ winner,
                         int wstride, int P) {
    int p = blockIdx.x * blockDim.x + threadIdx.x;
    if (p >= P) return;
    int4 c4 = reinterpret_cast<const int4*>(coords)[p];  // (b, z, y, x)
    int loc = c4.x * wstride + c4.z * WW + c4.w;
    atomicMax(&winner[loc], p + 1);   // device-scope by default (G12)
}

// One thread per (b, c, y, x/4): float4 coalesced store of the final canvas.
// wstride: stride (in ints) between consecutive batches of the winner array.
__global__ void k_gather(const float* __restrict__ feat, const int* __restrict__ winner,
                         int wstride, float* __restrict__ out, int cbase, int cnum,
                         int total) {
    int t = blockIdx.x * blockDim.x + threadIdx.x;
    if (t >= total) return;
    int x4 = t % W4;  int r = t / W4;
    int y  = r % HH;  r /= HH;
    int c  = cbase + (r % cnum);
    int b  = r / cnum;
    int loc = b * wstride + y * WW + x4 * 4;
    int4 win = *reinterpret_cast<const int4*>(&winner[loc]);
    float4 v;
    v.x = (win.x > 0) ? feat[(win.x - 1) * CC + c] : 0.0f;
    v.y = (win.y > 0) ? feat[(win.y - 1) * CC + c] : 0.0f;
    v.z = (win.z > 0) ? feat[(win.z - 1) * CC + c] : 0.0f;
    v.w = (win.w > 0) ? feat[(win.w - 1) * CC + c] : 0.0f;
    *reinterpret_cast<float4*>(&out[((b * CC + c) * HH + y) * WW + x4 * 4]) = v;
}

// Fallback path only: winner lives in the c=0 plane of out; rewrite that plane
// with the real c=0 features. One thread per cell quad -> race-free.
__global__ void k_fixplane0(const float* __restrict__ feat, float* __restrict__ out,
                            int total) {
    int t = blockIdx.x * blockDim.x + threadIdx.x;
    if (t >= total) return;
    int x4 = t % W4;  int r = t / W4;
    int y  = r % HH;  int b = r / HH;
    int loc = b * CC * HWp + y * WW + x4 * 4;
    int4 win = *reinterpret_cast<const int4*>(reinterpret_cast<const int*>(out) + loc);
    float4 v;
    v.x = (win.x > 0) ? feat[(win.x - 1) * CC] : 0.0f;
    v.y = (win.y > 0) ? feat[(win.y - 1) * CC] : 0.0f;
    v.z = (win.z > 0) ? feat[(win.z - 1) * CC] : 0.0f;
    v.w = (win.w > 0) ? feat[(win.w - 1) * CC] : 0.0f;
    *reinterpret_cast<float4*>(&out[loc]) = v;
}

extern "C" void kernel_launch(void* const* d_in, const int* in_sizes, int n_in,
                              void* d_out, int out_size, void* d_ws, size_t ws_size,
                              hipStream_t stream) {
    const float* feat   = (const float*)d_in[0];
    const int*   coords = (const int*)d_in[1];
    float*       out    = (float*)d_out;

    const int P = in_sizes[0] / CC;               // 96000
    const int B = out_size / (CC * HWp);          // 8

    const size_t winner_bytes = (size_t)B * HWp * sizeof(int);

    if (ws_size >= winner_bytes) {
        // --- primary path: winner array in workspace ---
        int* winner = (int*)d_ws;
        hipMemsetAsync(winner, 0, winner_bytes, stream);
        k_winner<<<(P + 255) / 256, 256, 0, stream>>>(coords, winner, HWp, P);
        int total = B * CC * HH * W4;             // 27,426,816
        k_gather<<<(total + 255) / 256, 256, 0, stream>>>(
            feat, winner, HWp, out, 0, CC, total);
    } else {
        // --- fallback: winner array in the c=0 plane of out ---
        for (int b = 0; b < B; ++b)
            hipMemsetAsync(out + (size_t)b * CC * HWp, 0, (size_t)HWp * sizeof(int), stream);
        k_winner<<<(P + 255) / 256, 256, 0, stream>>>(coords, (int*)out, CC * HWp, P);
        int total = B * (CC - 1) * HH * W4;
        k_gather<<<(total + 255) / 256, 256, 0, stream>>>(
            feat, (int*)out, CC * HWp, out, 1, CC - 1, total);
        int t0 = B * HH * W4;
        k_fixplane0<<<(t0 + 255) / 256, 256, 0, stream>>>(feat, out, t0);
    }
}

// Round 2
// 96.228 us; speedup vs baseline: 1.2648x; 1.2648x over previous
//
#include <hip/hip_runtime.h>

// PointPillarsScatter: canvas[b, :, y, x] = feat[p, :], last-writer-wins.
// Phase 1: winner[b,y,x] = max(p)+1 via atomicMax (deterministic last writer).
// Phase 2: gather — one thread per (b, y, x/4) cell-quad loops over all 64
// channels: winner read ONCE per 1 KB written, feat rows read as contiguous
// float4s, output written as nontemporal float4 (write-once, skip L2).

constexpr int HH  = 496;
constexpr int WW  = 432;
constexpr int CC  = 64;
constexpr int HWp = HH * WW;   // 214272
constexpr int W4  = WW / 4;    // 108

typedef float v4f __attribute__((ext_vector_type(4)));

// Zero-initialized device global: the "feature row" of empty cells.
__device__ float g_zero_row[CC];

__global__ void k_winner(const int* __restrict__ coords, int* __restrict__ winner,
                         int wstride, int P) {
    int p = blockIdx.x * blockDim.x + threadIdx.x;
    if (p >= P) return;
    int4 c4 = reinterpret_cast<const int4*>(coords)[p];  // (b, z, y, x)
    atomicMax(&winner[c4.x * wstride + c4.z * WW + c4.w], p + 1);
}

__global__ __launch_bounds__(256) void k_gather_cells(
        const float* __restrict__ feat, const int* __restrict__ winner,
        int wstride, float* __restrict__ out, int total) {
    int t = blockIdx.x * blockDim.x + threadIdx.x;
    if (t >= total) return;
    int x4 = t % W4;  int r = t / W4;
    int y  = r % HH;  int bb = r / HH;

    const int4 win = *reinterpret_cast<const int4*>(
        &winner[bb * wstride + y * WW + x4 * 4]);

    // Empty cells read from the zero row -> unconditional vector loads.
    const float* f0 = (win.x > 0) ? feat + (size_t)(win.x - 1) * CC : g_zero_row;
    const float* f1 = (win.y > 0) ? feat + (size_t)(win.y - 1) * CC : g_zero_row;
    const float* f2 = (win.z > 0) ? feat + (size_t)(win.z - 1) * CC : g_zero_row;
    const float* f3 = (win.w > 0) ? feat + (size_t)(win.w - 1) * CC : g_zero_row;

    float* ob = out + ((size_t)bb * CC * HH + y) * WW + x4 * 4;

    #pragma unroll 4
    for (int cq = 0; cq < CC / 4; ++cq) {
        v4f a = *reinterpret_cast<const v4f*>(f0 + cq * 4);
        v4f b = *reinterpret_cast<const v4f*>(f1 + cq * 4);
        v4f c = *reinterpret_cast<const v4f*>(f2 + cq * 4);
        v4f d = *reinterpret_cast<const v4f*>(f3 + cq * 4);
        float* o = ob + (size_t)cq * 4 * HWp;
        v4f s0 = {a.x, b.x, c.x, d.x};
        v4f s1 = {a.y, b.y, c.y, d.y};
        v4f s2 = {a.z, b.z, c.z, d.z};
        v4f s3 = {a.w, b.w, c.w, d.w};
        __builtin_nontemporal_store(s0, reinterpret_cast<v4f*>(o));
        __builtin_nontemporal_store(s1, reinterpret_cast<v4f*>(o + HWp));
        __builtin_nontemporal_store(s2, reinterpret_cast<v4f*>(o + 2 * HWp));
        __builtin_nontemporal_store(s3, reinterpret_cast<v4f*>(o + 3 * HWp));
    }
}

extern "C" void kernel_launch(void* const* d_in, const int* in_sizes, int n_in,
                              void* d_out, int out_size, void* d_ws, size_t ws_size,
                              hipStream_t stream) {
    const float* feat   = (const float*)d_in[0];
    const int*   coords = (const int*)d_in[1];
    float*       out    = (float*)d_out;

    const int P = in_sizes[0] / CC;        // 96000
    const int B = out_size / (CC * HWp);   // 8

    const size_t winner_bytes = (size_t)B * HWp * sizeof(int);
    const int total = B * HH * W4;         // 428,544 cell-quads

    if (ws_size >= winner_bytes) {
        // --- primary: winner array in workspace ---
        int* winner = (int*)d_ws;
        hipMemsetAsync(winner, 0, winner_bytes, stream);
        k_winner<<<(P + 255) / 256, 256, 0, stream>>>(coords, winner, HWp, P);
        k_gather_cells<<<(total + 255) / 256, 256, 0, stream>>>(
            feat, winner, HWp, out, total);
    } else {
        // --- fallback: winner lives in the c=0 plane of out; each gather
        // thread reads its own quad before overwriting it (no cross-thread
        // overlap), so a single gather pass is still race-free.
        for (int b = 0; b < B; ++b)
            hipMemsetAsync(out + (size_t)b * CC * HWp, 0,
                           (size_t)HWp * sizeof(int), stream);
        k_winner<<<(P + 255) / 256, 256, 0, stream>>>(
            coords, (int*)out, CC * HWp, P);
        k_gather_cells<<<(total + 255) / 256, 256, 0, stream>>>(
            feat, (int*)out, CC * HWp, out, total);
    }
}